// Round 10
// baseline (610.582 us; speedup 1.0000x reference)
//
#include <hip/hip_runtime.h>
#include <hip/hip_bf16.h>

#define NN 100000
#define NROWS_PAD 100096
#define EE 1600000
#define GG 512
#define NPB 256                                            // nodes per bucket
#define NB  ((NN + NPB - 1) / NPB)                         // 391 buckets
#define CAP 5120                                           // padded bucket capacity (mu=4096, sigma=64)
#define PCHUNK 4096                                        // edges per partition block
#define PBLOCKS ((EE + PCHUNK - 1) / PCHUNK)               // 391
#define SBANK 8                                            // stats replication banks
static constexpr float BN_EPS = 1e-5f;

typedef _Float16 half8 __attribute__((ext_vector_type(8)));
typedef float floatx4 __attribute__((ext_vector_type(4)));

// ---------------------------------------------------------------------------
// single-pass padded-bucket partition with LDS-staged writes.
// ebuf packed: src | (dst&255) << 17
// bucket b occupies ebuf[b*CAP .. b*CAP + count_b); bcursor[b] ends = count_b
// Scatter goes through a block-local staging buffer so global writes are
// contiguous runs per bucket (~42B) instead of random 4B (16x line RMW).
// ---------------------------------------------------------------------------

__global__ __launch_bounds__(256) void k_part(const int* __restrict__ EI,
                                              int* __restrict__ bcursor,
                                              int* __restrict__ ebuf)
{
    __shared__ int h[NB];
    __shared__ int s[512];
    __shared__ int pfx[512];
    __shared__ int gbase[NB];
    __shared__ int lcur[NB];
    __shared__ int lstage[PCHUNK];
    const int t = threadIdx.x;
    for (int i = t; i < NB; i += 256) h[i] = 0;
    __syncthreads();
    const int e0 = blockIdx.x * PCHUNK;
    const int e1 = (e0 + PCHUNK < EE) ? e0 + PCHUNK : EE;
    for (int e = e0 + t; e < e1; e += 256)
        atomicAdd(&h[EI[EE + e] >> 8], 1);
    __syncthreads();
    // reserve disjoint global ranges per bucket
    for (int i = t; i < NB; i += 256)
        gbase[i] = h[i] ? (i * CAP + atomicAdd(&bcursor[i], h[i])) : 0;
    // block-wide scan of h (512 slots, 2 per thread)
    int v0 = (t < NB) ? h[t] : 0;
    int v1 = (t + 256 < NB) ? h[t + 256] : 0;
    s[t] = v0; s[t + 256] = v1;
    __syncthreads();
    for (int off = 1; off < 512; off <<= 1) {
        int a = (t >= off) ? s[t - off] : 0;
        int b = s[t + 256 - off];
        __syncthreads();
        s[t] += a; s[t + 256] += b;
        __syncthreads();
    }
    pfx[t] = s[t] - v0;                  // exclusive staging start
    pfx[t + 256] = s[t + 256] - v1;
    __syncthreads();
    for (int i = t; i < NB; i += 256) lcur[i] = pfx[i];
    __syncthreads();
    // scatter into LDS staging, grouped by bucket
    for (int e = e0 + t; e < e1; e += 256) {
        int sv = EI[e], d = EI[EE + e];
        int b = d >> 8;
        int lpos = atomicAdd(&lcur[b], 1);
        lstage[lpos] = sv | ((d & (NPB - 1)) << 17);
    }
    __syncthreads();
    // contiguous write-out per bucket run (binary search for owning bucket)
    const int total = e1 - e0;
    for (int i = t; i < total; i += 256) {
        int lo = 0, hi = NB - 1;
        while (lo < hi) { int mid = (lo + hi + 1) >> 1; if (pfx[mid] <= i) lo = mid; else hi = mid - 1; }
        ebuf[gbase[lo] + (i - pfx[lo])] = lstage[i];
    }
}

// per-bucket: count -> block scan -> rs/re -> scatter into LDS staging ->
// one fully-coalesced linear write of the bucket's ssrc region.
__global__ __launch_bounds__(256) void k_csrbucket(const int* __restrict__ ebuf,
                                                   const int* __restrict__ bcursor,
                                                   int* __restrict__ rs,
                                                   int* __restrict__ re,
                                                   int* __restrict__ ssrc)
{
    __shared__ int cnt[NPB];
    __shared__ int cur[NPB];
    __shared__ int lst[CAP];
    const int b = blockIdx.x, t = threadIdx.x;
    cnt[t] = 0;
    __syncthreads();
    const int e0 = b * CAP;
    const int used = bcursor[b];
    const int e1 = e0 + used;
    for (int e = e0 + t; e < e1; e += 256) {
        unsigned p = (unsigned)__builtin_nontemporal_load(&ebuf[e]);
        atomicAdd(&cnt[p >> 17], 1);
    }
    __syncthreads();
    int myc = cnt[t];
    for (int off = 1; off < 256; off <<= 1) {
        int u = (t >= off) ? cnt[t - off] : 0;
        __syncthreads();
        cnt[t] += u;
        __syncthreads();
    }
    int lpos0 = cnt[t] - myc;            // local exclusive prefix (within bucket)
    int idx = b * NPB + t;
    if (idx < NN) { rs[idx] = e0 + lpos0; re[idx] = e0 + lpos0 + myc; }
    cur[t] = lpos0;
    __syncthreads();
    for (int e = e0 + t; e < e1; e += 256) {
        unsigned p = (unsigned)__builtin_nontemporal_load(&ebuf[e]);
        int lpos = atomicAdd(&cur[p >> 17], 1);
        lst[lpos] = (int)(p & 0x1FFFFu);
    }
    __syncthreads();
    for (int i = t; i < used; i += 256)
        ssrc[e0 + i] = lst[i];
}

// ---------------------------------------------------------------------------
// per-graph start offsets (once per call; batch is static across layers)
// ---------------------------------------------------------------------------

__global__ __launch_bounds__(512) void k_gstart(const int* __restrict__ batch,
                                                int* __restrict__ gstart)
{
    int g = threadIdx.x;
    int lo = 0, hi = NN;
    while (lo < hi) { int m = (lo + hi) >> 1; if (batch[m] < g) lo = m + 1; else hi = m; }
    gstart[g] = lo;
    if (g == 0) gstart[GG] = NN;
}

// ---------------------------------------------------------------------------
// inline BN fold from 8-bank stats (L2-hot; 16 loads + rsqrt)
// ---------------------------------------------------------------------------

__device__ __forceinline__ void bn_fold(const float* __restrict__ statsL,
                                        const float* __restrict__ g,
                                        const float* __restrict__ be, int k,
                                        float& sc, float& sh)
{
    float cs = 0.f, cq = 0.f;
    #pragma unroll
    for (int b = 0; b < SBANK; ++b) {
        cs += statsL[b * 256 + k];
        cq += statsL[b * 256 + 128 + k];
    }
    float inv_n = 1.0f / (float)NN;
    float mu = cs * inv_n;
    float var = cq * inv_n - mu * mu;
    sc = g[k] * rsqrtf(var + BN_EPS);
    sh = be[k] - mu * sc;
}

// ---------------------------------------------------------------------------
// stats-independent weight prep, hoisted before the layer loop (once):
// blocks 0-63: Wt1e (embed slice of W1_0); 64-255: Wt2 for layers 0..2
// ---------------------------------------------------------------------------

__global__ __launch_bounds__(256) void k_prepw(
    const float* __restrict__ W1_0,
    const float* __restrict__ W2_0, const float* __restrict__ W2_1,
    const float* __restrict__ W2_2,
    _Float16* __restrict__ Wt1e, _Float16* __restrict__ Wt2a)
{
    int b = blockIdx.x, t = threadIdx.x;
    if (b < 64) {
        int idx = b * 256 + t;
        int n = idx >> 7, k = idx & 127;
        Wt1e[idx] = (_Float16)W1_0[(200 + k) * 128 + n];
    } else {
        int l = (b - 64) >> 6;
        int idx = ((b - 64) & 63) * 256 + t;
        int n = idx >> 7, k = idx & 127;
        const float* W2 = (l == 0) ? W2_0 : (l == 1) ? W2_1 : W2_2;
        Wt2a[l * 16384 + idx] = (_Float16)W2[k * 128 + n];
    }
}

// stats-dependent prep (layers 1,2): blocks 0-63 Wt1 fold; block 64 cvec
__global__ __launch_bounds__(256) void k_prep1(
    const float* __restrict__ W1,
    const float* __restrict__ statsPrev,
    const float* __restrict__ gP, const float* __restrict__ beP,
    _Float16* __restrict__ Wt1, float* __restrict__ cvec)
{
    __shared__ float shs[128];
    int b = blockIdx.x, t = threadIdx.x;
    if (b < 64) {
        int idx = b * 256 + t;
        int n = idx >> 7, k = idx & 127;
        float sc, sh;
        bn_fold(statsPrev, gP, beP, k, sc, sh);
        Wt1[idx] = (_Float16)(sc * W1[k * 128 + n]);
    } else {
        if (t < 128) {
            float sc, sh;
            bn_fold(statsPrev, gP, beP, t, sc, sh);
            shs[t] = sh;
        }
        __syncthreads();
        if (t < 128) {
            float acc = 0.f;
            #pragma unroll 4
            for (int k = 0; k < 128; ++k)
                acc = fmaf(shs[k], W1[k * 128 + t], acc);
            cvec[t] = acc;
        }
    }
}

// ---------------------------------------------------------------------------
// MFMA GEMM. 128-row tiles: block 128x128, 4 waves 2x2, wave tile 64x64,
// acc[4][4]; B-fragments reused 4x. Epilogue via LDS, coalesced half8 out.
// ---------------------------------------------------------------------------

#define MM_CORE_G128(Ah, Wth)                                                \
    const int lane = tid & 63;                                               \
    const int wv = tid >> 6;                                                 \
    const int ml = lane & 15;                                                \
    const int quad = lane >> 4;                                              \
    const int wr = wv >> 1, wc = wv & 1;                                     \
    floatx4 acc[4][4];                                                       \
    for (int r = 0; r < 4; ++r)                                              \
        for (int t = 0; t < 4; ++t)                                          \
            acc[r][t] = (floatx4){0.f, 0.f, 0.f, 0.f};                       \
    {                                                                        \
        const size_t arb = (size_t)(row0 + 64 * wr + ml) * 128;              \
        _Pragma("unroll")                                                    \
        for (int kq = 0; kq < 4; ++kq) {                                     \
            int k0 = kq * 32;                                                \
            half8 a[4];                                                      \
            _Pragma("unroll")                                                \
            for (int r = 0; r < 4; ++r)                                      \
                a[r] = *(const half8*)&Ah[arb + (size_t)(16 * r) * 128 + k0 + quad * 8]; \
            _Pragma("unroll")                                                \
            for (int t = 0; t < 4; ++t) {                                    \
                half8 bf = *(const half8*)&Wth[(size_t)(64 * wc + 16 * t + ml) * 128 + k0 + quad * 8]; \
                _Pragma("unroll")                                            \
                for (int r = 0; r < 4; ++r)                                  \
                    acc[r][t] = __builtin_amdgcn_mfma_f32_16x16x32_f16(a[r], bf, acc[r][t], 0, 0, 0); \
            }                                                                \
        }                                                                    \
    }

// coalesced C write-out from LDS tile (128 rows x 128 cols fp16)
#define MM_STORE_LDS128(Csh, Out)                                            \
    __syncthreads();                                                         \
    _Pragma("unroll")                                                        \
    for (int c = 0; c < 8; ++c) {                                            \
        int chunk = tid * 8 + c * 2048;                                      \
        if (row0 + (chunk >> 7) < NN)                                        \
            *(half8*)&Out[(size_t)row0 * 128 + chunk] = *(const half8*)&Csh[chunk]; \
    }

// embed GEMM (64-row tile) reads fp32 X directly
__global__ __launch_bounds__(256) void k_mm_embed(
    const float* __restrict__ X, const _Float16* __restrict__ Wth,
    const int* __restrict__ Z, const float* __restrict__ W1,
    _Float16* __restrict__ Ph)
{
    __shared__ _Float16 Csh[64 * 128];
    const int tid = threadIdx.x;
    const int row0 = blockIdx.x * 64;
    const int lane = tid & 63;
    const int wv = tid >> 6;
    const int ml = lane & 15;
    const int quad = lane >> 4;
    const int wr = wv >> 1, wc = wv & 1;
    floatx4 acc[2][4];
    #pragma unroll
    for (int r = 0; r < 2; ++r)
        #pragma unroll
        for (int t = 0; t < 4; ++t)
            acc[r][t] = (floatx4){0.f, 0.f, 0.f, 0.f};
    int r0g = row0 + 32 * wr + ml;
    int r1g = r0g + 16;
    if (r0g > NN - 1) r0g = NN - 1;          // clamp: keep reads in-bounds
    if (r1g > NN - 1) r1g = NN - 1;
    const float* x0 = &X[(size_t)r0g * 128];
    const float* x1 = &X[(size_t)r1g * 128];
    #pragma unroll
    for (int kq = 0; kq < 4; ++kq) {
        int k0 = kq * 32 + quad * 8;
        float4 f0a = *(const float4*)&x0[k0];
        float4 f0b = *(const float4*)&x0[k0 + 4];
        float4 f1a = *(const float4*)&x1[k0];
        float4 f1b = *(const float4*)&x1[k0 + 4];
        half8 a0 = { (_Float16)f0a.x, (_Float16)f0a.y, (_Float16)f0a.z, (_Float16)f0a.w,
                     (_Float16)f0b.x, (_Float16)f0b.y, (_Float16)f0b.z, (_Float16)f0b.w };
        half8 a1 = { (_Float16)f1a.x, (_Float16)f1a.y, (_Float16)f1a.z, (_Float16)f1a.w,
                     (_Float16)f1b.x, (_Float16)f1b.y, (_Float16)f1b.z, (_Float16)f1b.w };
        #pragma unroll
        for (int t = 0; t < 4; ++t) {
            half8 bf = *(const half8*)&Wth[(size_t)(64 * wc + 16 * t + ml) * 128 + kq * 32 + quad * 8];
            acc[0][t] = __builtin_amdgcn_mfma_f32_16x16x32_f16(a0, bf, acc[0][t], 0, 0, 0);
            acc[1][t] = __builtin_amdgcn_mfma_f32_16x16x32_f16(a1, bf, acc[1][t], 0, 0, 0);
        }
    }
    #pragma unroll
    for (int r = 0; r < 2; ++r)
        #pragma unroll
        for (int j = 0; j < 4; ++j) {
            int lrow = 32 * wr + 16 * r + quad * 4 + j;
            int grow = row0 + lrow;
            int zv = (grow < NN) ? Z[grow] : 0;
            const float* w0 = &W1[zv * 128];
            const float* w1 = &W1[(100 + zv) * 128];
            #pragma unroll
            for (int t = 0; t < 4; ++t) {
                int gcol = 64 * wc + 16 * t + ml;
                Csh[lrow * 128 + gcol] = (_Float16)(acc[r][t][j] + w0[gcol] + w1[gcol]);
            }
        }
    __syncthreads();
    #pragma unroll
    for (int c = 0; c < 4; ++c) {
        int chunk = tid * 8 + c * 2048;
        if (row0 + (chunk >> 7) < NN)
            *(half8*)&Ph[(size_t)row0 * 128 + chunk] = *(const half8*)&Csh[chunk];
    }
}

__global__ __launch_bounds__(256) void k_mm1(
    const _Float16* __restrict__ Ah, const _Float16* __restrict__ Wth,
    _Float16* __restrict__ Ph)
{
    __shared__ _Float16 Csh[128 * 128];
    const int tid = threadIdx.x;
    const int row0 = blockIdx.x * 128;
    MM_CORE_G128(Ah, Wth)
    #pragma unroll
    for (int r = 0; r < 4; ++r)
        #pragma unroll
        for (int j = 0; j < 4; ++j) {
            int lrow = 64 * wr + 16 * r + quad * 4 + j;
            #pragma unroll
            for (int t = 0; t < 4; ++t)
                Csh[lrow * 128 + 64 * wc + 16 * t + ml] = (_Float16)acc[r][t][j];
        }
    MM_STORE_LDS128(Csh, Ph)
}

// A' = relu(M @ Wt2 + b2) -> Oh; BN stats into 8-bank replicated buffer
__global__ __launch_bounds__(256) void k_mm2(
    const _Float16* __restrict__ Ah, const _Float16* __restrict__ Wth,
    const float* __restrict__ b2, _Float16* __restrict__ Oh,
    float* __restrict__ statsL)
{
    __shared__ _Float16 Csh[128 * 128];
    __shared__ float cs[128];
    __shared__ float cq[128];
    const int tid = threadIdx.x;
    const int row0 = blockIdx.x * 128;
    if (tid < 128) { cs[tid] = 0.f; cq[tid] = 0.f; }
    __syncthreads();

    MM_CORE_G128(Ah, Wth)

    float b2v[4];
    #pragma unroll
    for (int t = 0; t < 4; ++t) b2v[t] = b2[64 * wc + 16 * t + ml];
    float st[4] = {0.f, 0.f, 0.f, 0.f};
    float qt[4] = {0.f, 0.f, 0.f, 0.f};
    #pragma unroll
    for (int r = 0; r < 4; ++r)
        #pragma unroll
        for (int j = 0; j < 4; ++j) {
            int lrow = 64 * wr + 16 * r + quad * 4 + j;
            bool ok = (row0 + lrow) < NN;
            #pragma unroll
            for (int t = 0; t < 4; ++t) {
                int gcol = 64 * wc + 16 * t + ml;
                float v = ok ? fmaxf(acc[r][t][j] + b2v[t], 0.f) : 0.f;
                Csh[lrow * 128 + gcol] = (_Float16)v;
                st[t] += v;
                qt[t] += v * v;
            }
        }
    #pragma unroll
    for (int t = 0; t < 4; ++t) {
        int gcol = 64 * wc + 16 * t + ml;
        atomicAdd(&cs[gcol], st[t]);
        atomicAdd(&cq[gcol], qt[t]);
    }
    MM_STORE_LDS128(Csh, Oh)
    if (tid < 128) {
        float* bank = statsL + (blockIdx.x & (SBANK - 1)) * 256;
        atomicAdd(&bank[tid], cs[tid]);
        atomicAdd(&bank[128 + tid], cq[tid]);
    }
}

// ---------------------------------------------------------------------------
// gather-aggregate: 16 lanes/node, half8 loads, 8-edge unroll (floor form)
// ---------------------------------------------------------------------------

__global__ __launch_bounds__(256) void k_aggregate(
    const _Float16* __restrict__ Ph, const int* __restrict__ rs,
    const int* __restrict__ re, const int* __restrict__ ssrc,
    const float* __restrict__ b1, const float* __restrict__ cvec,
    _Float16* __restrict__ Mh)
{
    int idx = blockIdx.x * 256 + threadIdx.x;
    int node = idx >> 4, q = idx & 15;
    if (node >= NN) return;
    int s0 = rs[node], s1 = re[node];
    float degp1 = (float)(s1 - s0 + 1);
    float acc[8];
    half8 pv = *(const half8*)&Ph[(size_t)node * 128 + q * 8];
    #pragma unroll
    for (int j = 0; j < 8; ++j)
        acc[j] = (float)pv[j] + fmaf(degp1, cvec[q * 8 + j], b1[q * 8 + j]);
    int e = s0;
    for (; e + 7 < s1; e += 8) {
        int sidx[8];
        #pragma unroll
        for (int u = 0; u < 8; ++u)
            sidx[u] = __builtin_nontemporal_load(&ssrc[e + u]);
        half8 v[8];
        #pragma unroll
        for (int u = 0; u < 8; ++u)
            v[u] = *(const half8*)&Ph[(size_t)sidx[u] * 128 + q * 8];
        #pragma unroll
        for (int j = 0; j < 8; ++j)
            acc[j] += (((float)v[0][j] + (float)v[1][j]) + ((float)v[2][j] + (float)v[3][j]))
                    + (((float)v[4][j] + (float)v[5][j]) + ((float)v[6][j] + (float)v[7][j]));
    }
    for (; e + 1 < s1; e += 2) {
        int sa = __builtin_nontemporal_load(&ssrc[e]);
        int sb = __builtin_nontemporal_load(&ssrc[e + 1]);
        half8 va = *(const half8*)&Ph[(size_t)sa * 128 + q * 8];
        half8 vb = *(const half8*)&Ph[(size_t)sb * 128 + q * 8];
        #pragma unroll
        for (int j = 0; j < 8; ++j) acc[j] += (float)va[j] + (float)vb[j];
    }
    if (e < s1) {
        int sa = __builtin_nontemporal_load(&ssrc[e]);
        half8 va = *(const half8*)&Ph[(size_t)sa * 128 + q * 8];
        #pragma unroll
        for (int j = 0; j < 8; ++j) acc[j] += (float)va[j];
    }
    half8 o;
    #pragma unroll
    for (int j = 0; j < 8; ++j) o[j] = (_Float16)fmaxf(acc[j], 0.f);
    __builtin_nontemporal_store(o, (half8*)&Mh[(size_t)node * 128 + q * 8]);
}

// ---------------------------------------------------------------------------
// mean-pool per graph (BN fold computed inline), 256 threads, gstart lookup
// ---------------------------------------------------------------------------

__global__ __launch_bounds__(256) void k_pool(
    const _Float16* __restrict__ Ah, const int* __restrict__ gstart,
    const float* __restrict__ statsL,
    const float* __restrict__ g_, const float* __restrict__ be,
    float* __restrict__ pooled, int loff)
{
    __shared__ float red[16][128];
    int g = blockIdx.x;
    int t = threadIdx.x;
    int rg = t >> 4, seg = t & 15;
    int s = gstart[g], e = gstart[g + 1];
    float acc[8] = {};
    for (int i = s + rg; i < e; i += 16) {
        half8 v = *(const half8*)&Ah[(size_t)i * 128 + seg * 8];
        #pragma unroll
        for (int j = 0; j < 8; ++j) acc[j] += (float)v[j];
    }
    #pragma unroll
    for (int j = 0; j < 8; ++j) red[rg][seg * 8 + j] = acc[j];
    __syncthreads();
    int cnt = e - s;
    float inv = 1.0f / (float)(cnt > 0 ? cnt : 1);
    if (t < 128) {
        float s_ = 0.f;
        #pragma unroll
        for (int r = 0; r < 16; ++r) s_ += red[r][t];
        float sc, sh;
        bn_fold(statsL, g_, be, t, sc, sh);
        pooled[g * 384 + loff + t] = fmaf(sc, s_ * inv, sh);
    }
}

__global__ __launch_bounds__(128) void k_final(
    const float* __restrict__ pooled,
    const float* __restrict__ Wl1, const float* __restrict__ bl1,
    const float* __restrict__ Wl2, const float* __restrict__ bl2,
    float* __restrict__ out)
{
    __shared__ float pr[384];
    __shared__ float red[128];
    int g = blockIdx.x, j = threadIdx.x;
    for (int i = j; i < 384; i += 128) pr[i] = pooled[g * 384 + i];
    __syncthreads();
    float acc = bl1[j];
    for (int k = 0; k < 384; ++k) acc = fmaf(pr[k], Wl1[k * 128 + j], acc);
    float r = fmaxf(acc, 0.f) * Wl2[j];
    red[j] = r;
    __syncthreads();
    for (int off = 64; off > 0; off >>= 1) {
        if (j < off) red[j] += red[j + off];
        __syncthreads();
    }
    if (j == 0) out[g] = red[0] + bl2[0];
}

extern "C" void kernel_launch(void* const* d_in, const int* in_sizes, int n_in,
                              void* d_out, int out_size, void* d_ws, size_t ws_size,
                              hipStream_t stream)
{
    const float* x     = (const float*)d_in[0];
    const int*   z     = (const int*)d_in[1];
    const int*   ei    = (const int*)d_in[2];
    const int*   batch = (const int*)d_in[3];
    const float* W1a[3] = {(const float*)d_in[4],  (const float*)d_in[10], (const float*)d_in[16]};
    const float* b1a[3] = {(const float*)d_in[5],  (const float*)d_in[11], (const float*)d_in[17]};
    const float* W2a[3] = {(const float*)d_in[6],  (const float*)d_in[12], (const float*)d_in[18]};
    const float* b2a[3] = {(const float*)d_in[7],  (const float*)d_in[13], (const float*)d_in[19]};
    const float* ga[3]  = {(const float*)d_in[8],  (const float*)d_in[14], (const float*)d_in[20]};
    const float* bea[3] = {(const float*)d_in[9],  (const float*)d_in[15], (const float*)d_in[21]};
    const float* Wl1 = (const float*)d_in[22];
    const float* bl1 = (const float*)d_in[23];
    const float* Wl2 = (const float*)d_in[24];
    const float* bl2 = (const float*)d_in[25];
    float* out = (float*)d_out;

    char* ws = (char*)d_ws;
    size_t off = 0;
    auto alloc = [&](size_t bytes) {
        void* p = ws + off;
        off += (bytes + 255) & ~(size_t)255;
        return p;
    };
    _Float16* Ph   = (_Float16*)alloc((size_t)NROWS_PAD * 128 * 2);
    _Float16* Mh   = (_Float16*)alloc((size_t)NROWS_PAD * 128 * 2);
    _Float16* Ahb  = (_Float16*)alloc((size_t)NROWS_PAD * 128 * 2);
    _Float16* Wt1e = (_Float16*)alloc((size_t)128 * 128 * 2);      // embed slice (static)
    _Float16* Wt1d = (_Float16*)alloc((size_t)128 * 128 * 2);      // BN-folded W1 (per layer)
    _Float16* Wt2a = (_Float16*)alloc((size_t)3 * 128 * 128 * 2);  // all 3 layers (static)
    int*   ebuf     = (int*)alloc((size_t)NB * CAP * 4);           // padded buckets
    int*   ssrc     = (int*)alloc((size_t)NB * CAP * 4);           // padded CSR adjacency
    int*   rs       = (int*)alloc((size_t)NN * 4);
    int*   re       = (int*)alloc((size_t)NN * 4);
    float* stats    = (float*)alloc((size_t)3 * SBANK * 256 * 4);  // [3][8][colsum|colsq]
    int*   bcursor  = (int*)alloc((size_t)NB * 4);                 // adjacent to stats: one memset
    int*   gstart   = (int*)alloc((size_t)(GG + 1) * 4);
    float* cvec     = (float*)alloc(128 * 4);
    float* pooled   = (float*)alloc((size_t)GG * 384 * 4);

    const int embedBlocks = (NN + 63) / 64;            // 1563
    const int mmBlocks    = (NN + 127) / 128;          // 782
    const int aggBlocks   = (NN * 16 + 255) / 256;     // 6250

    // ---- one-time per call ----
    // stats (24576 B, 256-multiple) and bcursor are adjacent: single memset
    hipMemsetAsync(stats, 0, (size_t)3 * SBANK * 256 * 4 + (size_t)NB * 4, stream);
    k_prepw<<<256, 256, 0, stream>>>(W1a[0], W2a[0], W2a[1], W2a[2], Wt1e, Wt2a);
    k_part<<<PBLOCKS, 256, 0, stream>>>(ei, bcursor, ebuf);
    k_gstart<<<1, 512, 0, stream>>>(batch, gstart);
    k_csrbucket<<<NB, 256, 0, stream>>>(ebuf, bcursor, rs, re, ssrc);

    for (int l = 0; l < 3; ++l) {
        float* statsL = stats + (size_t)l * SBANK * 256;
        if (l == 0) {
            k_mm_embed<<<embedBlocks, 256, 0, stream>>>(x, Wt1e, z, W1a[0], Ph);
        } else {
            const float* statsPrev = stats + (size_t)(l - 1) * SBANK * 256;
            k_prep1<<<65, 256, 0, stream>>>(W1a[l], statsPrev, ga[l - 1], bea[l - 1],
                                            Wt1d, cvec);
            k_mm1<<<mmBlocks, 256, 0, stream>>>(Ahb, Wt1d, Ph);
        }
        k_aggregate<<<aggBlocks, 256, 0, stream>>>(Ph, rs, re, ssrc, b1a[l], cvec, Mh);
        k_mm2<<<mmBlocks, 256, 0, stream>>>(Mh, Wt2a + (size_t)l * 16384, b2a[l],
                                            Ahb, statsL);
        k_pool<<<GG, 256, 0, stream>>>(Ahb, gstart, statsL, ga[l], bea[l],
                                       pooled, l * 128);
    }
    k_final<<<GG, 128, 0, stream>>>(pooled, Wl1, bl1, Wl2, bl2, out);
}

// Round 11
// 596.864 us; speedup vs baseline: 1.0230x; 1.0230x over previous
//
#include <hip/hip_runtime.h>
#include <hip/hip_bf16.h>

#define NN 100000
#define NROWS_PAD 100096
#define EE 1600000
#define GG 512
#define NPB 256                                            // nodes per bucket
#define NB  ((NN + NPB - 1) / NPB)                         // 391 buckets
#define CAP 5120                                           // padded bucket capacity (mu=4096, sigma=64)
#define PCHUNK 4096                                        // edges per partition block
#define PBLOCKS ((EE + PCHUNK - 1) / PCHUNK)               // 391
#define SBANK 8                                            // stats replication banks
static constexpr float BN_EPS = 1e-5f;

typedef _Float16 half8 __attribute__((ext_vector_type(8)));
typedef float floatx4 __attribute__((ext_vector_type(4)));

// ---------------------------------------------------------------------------
// single-pass padded-bucket partition. ebuf packed: src | (dst&255) << 17
// bucket b occupies ebuf[b*CAP .. b*CAP + count_b); bcursor[b] ends = count_b
// (R10 showed LDS-staged scatter is a net loss: direct 4B scatter lands in
// L2 and is absorbed; keep the simple form.)
// ---------------------------------------------------------------------------

__global__ __launch_bounds__(256) void k_part(const int* __restrict__ EI,
                                              int* __restrict__ bcursor,
                                              int* __restrict__ ebuf)
{
    __shared__ int h[NB];
    __shared__ int cur[NB];
    const int t = threadIdx.x;
    for (int i = t; i < NB; i += 256) h[i] = 0;
    __syncthreads();
    const int e0 = blockIdx.x * PCHUNK;
    const int e1 = (e0 + PCHUNK < EE) ? e0 + PCHUNK : EE;
    for (int e = e0 + t; e < e1; e += 256)
        atomicAdd(&h[EI[EE + e] >> 8], 1);
    __syncthreads();
    for (int i = t; i < NB; i += 256)
        cur[i] = h[i] ? (i * CAP + atomicAdd(&bcursor[i], h[i])) : 0;
    __syncthreads();
    for (int e = e0 + t; e < e1; e += 256) {
        int s = EI[e], d = EI[EE + e];
        int pos = atomicAdd(&cur[d >> 8], 1);
        ebuf[pos] = s | ((d & (NPB - 1)) << 17);
    }
}

// per-bucket: count -> block scan -> rs/re (padded-space offsets) -> fill ssrc
__global__ __launch_bounds__(256) void k_csrbucket(const int* __restrict__ ebuf,
                                                   const int* __restrict__ bcursor,
                                                   int* __restrict__ rs,
                                                   int* __restrict__ re,
                                                   int* __restrict__ ssrc)
{
    __shared__ int cnt[NPB];
    __shared__ int cur[NPB];
    const int b = blockIdx.x, t = threadIdx.x;
    cnt[t] = 0;
    __syncthreads();
    const int e0 = b * CAP, e1 = e0 + bcursor[b];
    for (int e = e0 + t; e < e1; e += 256) {
        unsigned p = (unsigned)__builtin_nontemporal_load(&ebuf[e]);
        atomicAdd(&cnt[p >> 17], 1);
    }
    __syncthreads();
    int myc = cnt[t];
    for (int off = 1; off < 256; off <<= 1) {
        int u = (t >= off) ? cnt[t - off] : 0;
        __syncthreads();
        cnt[t] += u;
        __syncthreads();
    }
    int pos0 = e0 + cnt[t] - myc;        // padded-space exclusive prefix
    int idx = b * NPB + t;
    if (idx < NN) { rs[idx] = pos0; re[idx] = pos0 + myc; }
    cur[t] = pos0;
    __syncthreads();
    for (int e = e0 + t; e < e1; e += 256) {
        unsigned p = (unsigned)__builtin_nontemporal_load(&ebuf[e]);
        int pos = atomicAdd(&cur[p >> 17], 1);
        ssrc[pos] = (int)(p & 0x1FFFFu);
    }
}

// ---------------------------------------------------------------------------
// per-graph start offsets (once per call; batch is static across layers)
// ---------------------------------------------------------------------------

__global__ __launch_bounds__(512) void k_gstart(const int* __restrict__ batch,
                                                int* __restrict__ gstart)
{
    int g = threadIdx.x;
    int lo = 0, hi = NN;
    while (lo < hi) { int m = (lo + hi) >> 1; if (batch[m] < g) lo = m + 1; else hi = m; }
    gstart[g] = lo;
    if (g == 0) gstart[GG] = NN;
}

// ---------------------------------------------------------------------------
// inline BN fold from 8-bank stats (L2-hot; 16 loads + rsqrt)
// ---------------------------------------------------------------------------

__device__ __forceinline__ void bn_fold(const float* __restrict__ statsL,
                                        const float* __restrict__ g,
                                        const float* __restrict__ be, int k,
                                        float& sc, float& sh)
{
    float cs = 0.f, cq = 0.f;
    #pragma unroll
    for (int b = 0; b < SBANK; ++b) {
        cs += statsL[b * 256 + k];
        cq += statsL[b * 256 + 128 + k];
    }
    float inv_n = 1.0f / (float)NN;
    float mu = cs * inv_n;
    float var = cq * inv_n - mu * mu;
    sc = g[k] * rsqrtf(var + BN_EPS);
    sh = be[k] - mu * sc;
}

// ---------------------------------------------------------------------------
// stats-independent weight prep, hoisted before the layer loop (once):
// blocks 0-63: Wt1e (embed slice of W1_0); 64-255: Wt2 for layers 0..2
// ---------------------------------------------------------------------------

__global__ __launch_bounds__(256) void k_prepw(
    const float* __restrict__ W1_0,
    const float* __restrict__ W2_0, const float* __restrict__ W2_1,
    const float* __restrict__ W2_2,
    _Float16* __restrict__ Wt1e, _Float16* __restrict__ Wt2a)
{
    int b = blockIdx.x, t = threadIdx.x;
    if (b < 64) {
        int idx = b * 256 + t;
        int n = idx >> 7, k = idx & 127;
        Wt1e[idx] = (_Float16)W1_0[(200 + k) * 128 + n];
    } else {
        int l = (b - 64) >> 6;
        int idx = ((b - 64) & 63) * 256 + t;
        int n = idx >> 7, k = idx & 127;
        const float* W2 = (l == 0) ? W2_0 : (l == 1) ? W2_1 : W2_2;
        Wt2a[l * 16384 + idx] = (_Float16)W2[k * 128 + n];
    }
}

// stats-dependent prep (layers 1,2): blocks 0-63 Wt1 fold; block 64 cvec
__global__ __launch_bounds__(256) void k_prep1(
    const float* __restrict__ W1,
    const float* __restrict__ statsPrev,
    const float* __restrict__ gP, const float* __restrict__ beP,
    _Float16* __restrict__ Wt1, float* __restrict__ cvec)
{
    __shared__ float shs[128];
    int b = blockIdx.x, t = threadIdx.x;
    if (b < 64) {
        int idx = b * 256 + t;
        int n = idx >> 7, k = idx & 127;
        float sc, sh;
        bn_fold(statsPrev, gP, beP, k, sc, sh);
        Wt1[idx] = (_Float16)(sc * W1[k * 128 + n]);
    } else {
        if (t < 128) {
            float sc, sh;
            bn_fold(statsPrev, gP, beP, t, sc, sh);
            shs[t] = sh;
        }
        __syncthreads();
        if (t < 128) {
            float acc = 0.f;
            #pragma unroll 4
            for (int k = 0; k < 128; ++k)
                acc = fmaf(shs[k], W1[k * 128 + t], acc);
            cvec[t] = acc;
        }
    }
}

// ---------------------------------------------------------------------------
// MFMA GEMM. 128-row tiles: block 128x128, 4 waves 2x2, wave tile 64x64,
// acc[4][4]; B-fragments reused 4x. Epilogue via LDS, coalesced half8 out.
// ---------------------------------------------------------------------------

#define MM_CORE_G128(Ah, Wth)                                                \
    const int lane = tid & 63;                                               \
    const int wv = tid >> 6;                                                 \
    const int ml = lane & 15;                                                \
    const int quad = lane >> 4;                                              \
    const int wr = wv >> 1, wc = wv & 1;                                     \
    floatx4 acc[4][4];                                                       \
    for (int r = 0; r < 4; ++r)                                              \
        for (int t = 0; t < 4; ++t)                                          \
            acc[r][t] = (floatx4){0.f, 0.f, 0.f, 0.f};                       \
    {                                                                        \
        const size_t arb = (size_t)(row0 + 64 * wr + ml) * 128;              \
        _Pragma("unroll")                                                    \
        for (int kq = 0; kq < 4; ++kq) {                                     \
            int k0 = kq * 32;                                                \
            half8 a[4];                                                      \
            _Pragma("unroll")                                                \
            for (int r = 0; r < 4; ++r)                                      \
                a[r] = *(const half8*)&Ah[arb + (size_t)(16 * r) * 128 + k0 + quad * 8]; \
            _Pragma("unroll")                                                \
            for (int t = 0; t < 4; ++t) {                                    \
                half8 bf = *(const half8*)&Wth[(size_t)(64 * wc + 16 * t + ml) * 128 + k0 + quad * 8]; \
                _Pragma("unroll")                                            \
                for (int r = 0; r < 4; ++r)                                  \
                    acc[r][t] = __builtin_amdgcn_mfma_f32_16x16x32_f16(a[r], bf, acc[r][t], 0, 0, 0); \
            }                                                                \
        }                                                                    \
    }

// coalesced C write-out from LDS tile (128 rows x 128 cols fp16)
#define MM_STORE_LDS128(Csh, Out)                                            \
    __syncthreads();                                                         \
    _Pragma("unroll")                                                        \
    for (int c = 0; c < 8; ++c) {                                            \
        int chunk = tid * 8 + c * 2048;                                      \
        if (row0 + (chunk >> 7) < NN)                                        \
            *(half8*)&Out[(size_t)row0 * 128 + chunk] = *(const half8*)&Csh[chunk]; \
    }

// embed GEMM (64-row tile) reads fp32 X directly
__global__ __launch_bounds__(256) void k_mm_embed(
    const float* __restrict__ X, const _Float16* __restrict__ Wth,
    const int* __restrict__ Z, const float* __restrict__ W1,
    _Float16* __restrict__ Ph)
{
    __shared__ _Float16 Csh[64 * 128];
    const int tid = threadIdx.x;
    const int row0 = blockIdx.x * 64;
    const int lane = tid & 63;
    const int wv = tid >> 6;
    const int ml = lane & 15;
    const int quad = lane >> 4;
    const int wr = wv >> 1, wc = wv & 1;
    floatx4 acc[2][4];
    #pragma unroll
    for (int r = 0; r < 2; ++r)
        #pragma unroll
        for (int t = 0; t < 4; ++t)
            acc[r][t] = (floatx4){0.f, 0.f, 0.f, 0.f};
    int r0g = row0 + 32 * wr + ml;
    int r1g = r0g + 16;
    if (r0g > NN - 1) r0g = NN - 1;          // clamp: keep reads in-bounds
    if (r1g > NN - 1) r1g = NN - 1;
    const float* x0 = &X[(size_t)r0g * 128];
    const float* x1 = &X[(size_t)r1g * 128];
    #pragma unroll
    for (int kq = 0; kq < 4; ++kq) {
        int k0 = kq * 32 + quad * 8;
        float4 f0a = *(const float4*)&x0[k0];
        float4 f0b = *(const float4*)&x0[k0 + 4];
        float4 f1a = *(const float4*)&x1[k0];
        float4 f1b = *(const float4*)&x1[k0 + 4];
        half8 a0 = { (_Float16)f0a.x, (_Float16)f0a.y, (_Float16)f0a.z, (_Float16)f0a.w,
                     (_Float16)f0b.x, (_Float16)f0b.y, (_Float16)f0b.z, (_Float16)f0b.w };
        half8 a1 = { (_Float16)f1a.x, (_Float16)f1a.y, (_Float16)f1a.z, (_Float16)f1a.w,
                     (_Float16)f1b.x, (_Float16)f1b.y, (_Float16)f1b.z, (_Float16)f1b.w };
        #pragma unroll
        for (int t = 0; t < 4; ++t) {
            half8 bf = *(const half8*)&Wth[(size_t)(64 * wc + 16 * t + ml) * 128 + kq * 32 + quad * 8];
            acc[0][t] = __builtin_amdgcn_mfma_f32_16x16x32_f16(a0, bf, acc[0][t], 0, 0, 0);
            acc[1][t] = __builtin_amdgcn_mfma_f32_16x16x32_f16(a1, bf, acc[1][t], 0, 0, 0);
        }
    }
    #pragma unroll
    for (int r = 0; r < 2; ++r)
        #pragma unroll
        for (int j = 0; j < 4; ++j) {
            int lrow = 32 * wr + 16 * r + quad * 4 + j;
            int grow = row0 + lrow;
            int zv = (grow < NN) ? Z[grow] : 0;
            const float* w0 = &W1[zv * 128];
            const float* w1 = &W1[(100 + zv) * 128];
            #pragma unroll
            for (int t = 0; t < 4; ++t) {
                int gcol = 64 * wc + 16 * t + ml;
                Csh[lrow * 128 + gcol] = (_Float16)(acc[r][t][j] + w0[gcol] + w1[gcol]);
            }
        }
    __syncthreads();
    #pragma unroll
    for (int c = 0; c < 4; ++c) {
        int chunk = tid * 8 + c * 2048;
        if (row0 + (chunk >> 7) < NN)
            *(half8*)&Ph[(size_t)row0 * 128 + chunk] = *(const half8*)&Csh[chunk];
    }
}

__global__ __launch_bounds__(256) void k_mm1(
    const _Float16* __restrict__ Ah, const _Float16* __restrict__ Wth,
    _Float16* __restrict__ Ph)
{
    __shared__ _Float16 Csh[128 * 128];
    const int tid = threadIdx.x;
    const int row0 = blockIdx.x * 128;
    MM_CORE_G128(Ah, Wth)
    #pragma unroll
    for (int r = 0; r < 4; ++r)
        #pragma unroll
        for (int j = 0; j < 4; ++j) {
            int lrow = 64 * wr + 16 * r + quad * 4 + j;
            #pragma unroll
            for (int t = 0; t < 4; ++t)
                Csh[lrow * 128 + 64 * wc + 16 * t + ml] = (_Float16)acc[r][t][j];
        }
    MM_STORE_LDS128(Csh, Ph)
}

// A' = relu(M @ Wt2 + b2) -> Oh; BN stats into 8-bank replicated buffer
__global__ __launch_bounds__(256) void k_mm2(
    const _Float16* __restrict__ Ah, const _Float16* __restrict__ Wth,
    const float* __restrict__ b2, _Float16* __restrict__ Oh,
    float* __restrict__ statsL)
{
    __shared__ _Float16 Csh[128 * 128];
    __shared__ float cs[128];
    __shared__ float cq[128];
    const int tid = threadIdx.x;
    const int row0 = blockIdx.x * 128;
    if (tid < 128) { cs[tid] = 0.f; cq[tid] = 0.f; }
    __syncthreads();

    MM_CORE_G128(Ah, Wth)

    float b2v[4];
    #pragma unroll
    for (int t = 0; t < 4; ++t) b2v[t] = b2[64 * wc + 16 * t + ml];
    float st[4] = {0.f, 0.f, 0.f, 0.f};
    float qt[4] = {0.f, 0.f, 0.f, 0.f};
    #pragma unroll
    for (int r = 0; r < 4; ++r)
        #pragma unroll
        for (int j = 0; j < 4; ++j) {
            int lrow = 64 * wr + 16 * r + quad * 4 + j;
            bool ok = (row0 + lrow) < NN;
            #pragma unroll
            for (int t = 0; t < 4; ++t) {
                int gcol = 64 * wc + 16 * t + ml;
                float v = ok ? fmaxf(acc[r][t][j] + b2v[t], 0.f) : 0.f;
                Csh[lrow * 128 + gcol] = (_Float16)v;
                st[t] += v;
                qt[t] += v * v;
            }
        }
    #pragma unroll
    for (int t = 0; t < 4; ++t) {
        int gcol = 64 * wc + 16 * t + ml;
        atomicAdd(&cs[gcol], st[t]);
        atomicAdd(&cq[gcol], qt[t]);
    }
    MM_STORE_LDS128(Csh, Oh)
    if (tid < 128) {
        float* bank = statsL + (blockIdx.x & (SBANK - 1)) * 256;
        atomicAdd(&bank[tid], cs[tid]);
        atomicAdd(&bank[128 + tid], cq[tid]);
    }
}

// ---------------------------------------------------------------------------
// gather-aggregate: 16 lanes/node, half8 loads, 8-edge unroll (floor form)
// ---------------------------------------------------------------------------

__global__ __launch_bounds__(256) void k_aggregate(
    const _Float16* __restrict__ Ph, const int* __restrict__ rs,
    const int* __restrict__ re, const int* __restrict__ ssrc,
    const float* __restrict__ b1, const float* __restrict__ cvec,
    _Float16* __restrict__ Mh)
{
    int idx = blockIdx.x * 256 + threadIdx.x;
    int node = idx >> 4, q = idx & 15;
    if (node >= NN) return;
    int s0 = rs[node], s1 = re[node];
    float degp1 = (float)(s1 - s0 + 1);
    float acc[8];
    half8 pv = *(const half8*)&Ph[(size_t)node * 128 + q * 8];
    #pragma unroll
    for (int j = 0; j < 8; ++j)
        acc[j] = (float)pv[j] + fmaf(degp1, cvec[q * 8 + j], b1[q * 8 + j]);
    int e = s0;
    for (; e + 7 < s1; e += 8) {
        int sidx[8];
        #pragma unroll
        for (int u = 0; u < 8; ++u)
            sidx[u] = __builtin_nontemporal_load(&ssrc[e + u]);
        half8 v[8];
        #pragma unroll
        for (int u = 0; u < 8; ++u)
            v[u] = *(const half8*)&Ph[(size_t)sidx[u] * 128 + q * 8];
        #pragma unroll
        for (int j = 0; j < 8; ++j)
            acc[j] += (((float)v[0][j] + (float)v[1][j]) + ((float)v[2][j] + (float)v[3][j]))
                    + (((float)v[4][j] + (float)v[5][j]) + ((float)v[6][j] + (float)v[7][j]));
    }
    for (; e + 1 < s1; e += 2) {
        int sa = __builtin_nontemporal_load(&ssrc[e]);
        int sb = __builtin_nontemporal_load(&ssrc[e + 1]);
        half8 va = *(const half8*)&Ph[(size_t)sa * 128 + q * 8];
        half8 vb = *(const half8*)&Ph[(size_t)sb * 128 + q * 8];
        #pragma unroll
        for (int j = 0; j < 8; ++j) acc[j] += (float)va[j] + (float)vb[j];
    }
    if (e < s1) {
        int sa = __builtin_nontemporal_load(&ssrc[e]);
        half8 va = *(const half8*)&Ph[(size_t)sa * 128 + q * 8];
        #pragma unroll
        for (int j = 0; j < 8; ++j) acc[j] += (float)va[j];
    }
    half8 o;
    #pragma unroll
    for (int j = 0; j < 8; ++j) o[j] = (_Float16)fmaxf(acc[j], 0.f);
    __builtin_nontemporal_store(o, (half8*)&Mh[(size_t)node * 128 + q * 8]);
}

// ---------------------------------------------------------------------------
// mean-pool per graph (BN fold computed inline), 256 threads, gstart lookup
// ---------------------------------------------------------------------------

__global__ __launch_bounds__(256) void k_pool(
    const _Float16* __restrict__ Ah, const int* __restrict__ gstart,
    const float* __restrict__ statsL,
    const float* __restrict__ g_, const float* __restrict__ be,
    float* __restrict__ pooled, int loff)
{
    __shared__ float red[16][128];
    int g = blockIdx.x;
    int t = threadIdx.x;
    int rg = t >> 4, seg = t & 15;
    int s = gstart[g], e = gstart[g + 1];
    float acc[8] = {};
    for (int i = s + rg; i < e; i += 16) {
        half8 v = *(const half8*)&Ah[(size_t)i * 128 + seg * 8];
        #pragma unroll
        for (int j = 0; j < 8; ++j) acc[j] += (float)v[j];
    }
    #pragma unroll
    for (int j = 0; j < 8; ++j) red[rg][seg * 8 + j] = acc[j];
    __syncthreads();
    int cnt = e - s;
    float inv = 1.0f / (float)(cnt > 0 ? cnt : 1);
    if (t < 128) {
        float s_ = 0.f;
        #pragma unroll
        for (int r = 0; r < 16; ++r) s_ += red[r][t];
        float sc, sh;
        bn_fold(statsL, g_, be, t, sc, sh);
        pooled[g * 384 + loff + t] = fmaf(sc, s_ * inv, sh);
    }
}

__global__ __launch_bounds__(128) void k_final(
    const float* __restrict__ pooled,
    const float* __restrict__ Wl1, const float* __restrict__ bl1,
    const float* __restrict__ Wl2, const float* __restrict__ bl2,
    float* __restrict__ out)
{
    __shared__ float pr[384];
    __shared__ float red[128];
    int g = blockIdx.x, j = threadIdx.x;
    for (int i = j; i < 384; i += 128) pr[i] = pooled[g * 384 + i];
    __syncthreads();
    float acc = bl1[j];
    for (int k = 0; k < 384; ++k) acc = fmaf(pr[k], Wl1[k * 128 + j], acc);
    float r = fmaxf(acc, 0.f) * Wl2[j];
    red[j] = r;
    __syncthreads();
    for (int off = 64; off > 0; off >>= 1) {
        if (j < off) red[j] += red[j + off];
        __syncthreads();
    }
    if (j == 0) out[g] = red[0] + bl2[0];
}

extern "C" void kernel_launch(void* const* d_in, const int* in_sizes, int n_in,
                              void* d_out, int out_size, void* d_ws, size_t ws_size,
                              hipStream_t stream)
{
    const float* x     = (const float*)d_in[0];
    const int*   z     = (const int*)d_in[1];
    const int*   ei    = (const int*)d_in[2];
    const int*   batch = (const int*)d_in[3];
    const float* W1a[3] = {(const float*)d_in[4],  (const float*)d_in[10], (const float*)d_in[16]};
    const float* b1a[3] = {(const float*)d_in[5],  (const float*)d_in[11], (const float*)d_in[17]};
    const float* W2a[3] = {(const float*)d_in[6],  (const float*)d_in[12], (const float*)d_in[18]};
    const float* b2a[3] = {(const float*)d_in[7],  (const float*)d_in[13], (const float*)d_in[19]};
    const float* ga[3]  = {(const float*)d_in[8],  (const float*)d_in[14], (const float*)d_in[20]};
    const float* bea[3] = {(const float*)d_in[9],  (const float*)d_in[15], (const float*)d_in[21]};
    const float* Wl1 = (const float*)d_in[22];
    const float* bl1 = (const float*)d_in[23];
    const float* Wl2 = (const float*)d_in[24];
    const float* bl2 = (const float*)d_in[25];
    float* out = (float*)d_out;

    char* ws = (char*)d_ws;
    size_t off = 0;
    auto alloc = [&](size_t bytes) {
        void* p = ws + off;
        off += (bytes + 255) & ~(size_t)255;
        return p;
    };
    _Float16* Ph   = (_Float16*)alloc((size_t)NROWS_PAD * 128 * 2);
    _Float16* Mh   = (_Float16*)alloc((size_t)NROWS_PAD * 128 * 2);
    _Float16* Ahb  = (_Float16*)alloc((size_t)NROWS_PAD * 128 * 2);
    _Float16* Wt1e = (_Float16*)alloc((size_t)128 * 128 * 2);      // embed slice (static)
    _Float16* Wt1d = (_Float16*)alloc((size_t)128 * 128 * 2);      // BN-folded W1 (per layer)
    _Float16* Wt2a = (_Float16*)alloc((size_t)3 * 128 * 128 * 2);  // all 3 layers (static)
    int*   ebuf     = (int*)alloc((size_t)NB * CAP * 4);           // padded buckets
    int*   ssrc     = (int*)alloc((size_t)NB * CAP * 4);           // padded CSR adjacency
    int*   rs       = (int*)alloc((size_t)NN * 4);
    int*   re       = (int*)alloc((size_t)NN * 4);
    float* stats    = (float*)alloc((size_t)3 * SBANK * 256 * 4);  // [3][8][colsum|colsq]
    int*   bcursor  = (int*)alloc((size_t)NB * 4);                 // adjacent to stats: one memset
    int*   gstart   = (int*)alloc((size_t)(GG + 1) * 4);
    float* cvec     = (float*)alloc(128 * 4);
    float* pooled   = (float*)alloc((size_t)GG * 384 * 4);

    const int embedBlocks = (NN + 63) / 64;            // 1563
    const int mmBlocks    = (NN + 127) / 128;          // 782
    const int aggBlocks   = (NN * 16 + 255) / 256;     // 6250

    // ---- one-time per call ----
    // stats (24576 B, 256-multiple) and bcursor are adjacent: single memset
    hipMemsetAsync(stats, 0, (size_t)3 * SBANK * 256 * 4 + (size_t)NB * 4, stream);
    k_prepw<<<256, 256, 0, stream>>>(W1a[0], W2a[0], W2a[1], W2a[2], Wt1e, Wt2a);
    k_part<<<PBLOCKS, 256, 0, stream>>>(ei, bcursor, ebuf);
    k_gstart<<<1, 512, 0, stream>>>(batch, gstart);
    k_csrbucket<<<NB, 256, 0, stream>>>(ebuf, bcursor, rs, re, ssrc);

    for (int l = 0; l < 3; ++l) {
        float* statsL = stats + (size_t)l * SBANK * 256;
        if (l == 0) {
            k_mm_embed<<<embedBlocks, 256, 0, stream>>>(x, Wt1e, z, W1a[0], Ph);
        } else {
            const float* statsPrev = stats + (size_t)(l - 1) * SBANK * 256;
            k_prep1<<<65, 256, 0, stream>>>(W1a[l], statsPrev, ga[l - 1], bea[l - 1],
                                            Wt1d, cvec);
            k_mm1<<<mmBlocks, 256, 0, stream>>>(Ahb, Wt1d, Ph);
        }
        k_aggregate<<<aggBlocks, 256, 0, stream>>>(Ph, rs, re, ssrc, b1a[l], cvec, Mh);
        k_mm2<<<mmBlocks, 256, 0, stream>>>(Mh, Wt2a + (size_t)l * 16384, b2a[l],
                                            Ahb, statsL);
        k_pool<<<GG, 256, 0, stream>>>(Ahb, gstart, statsL, ga[l], bea[l],
                                       pooled, l * 128);
    }
    k_final<<<GG, 128, 0, stream>>>(pooled, Wl1, bl1, Wl2, bl2, out);
}